// Round 2
// 412.261 us; speedup vs baseline: 1.0620x; 1.0620x over previous
//
#include <hip/hip_runtime.h>
#include <cstddef>
#include <cstdint>

#define NB     4
#define CDIM   256
#define KD     32
#define NPIX   4096
#define SSHIFT 20.0f

typedef __attribute__((ext_vector_type(8))) short  bfrag;   // 8 bf16
typedef __attribute__((ext_vector_type(4))) float  facc;    // 4 fp32

#define MFMA(a,b,c) __builtin_amdgcn_mfma_f32_16x16x32_bf16((a),(b),(c),0,0,0)

__device__ __forceinline__ unsigned short f2bf(float x) {
    union { float f; unsigned u; } v; v.f = x;
    unsigned u = v.u + 0x7fffu + ((v.u >> 16) & 1u);
    return (unsigned short)(u >> 16);
}
__device__ __forceinline__ float bf2f(unsigned short h) {
    union { float f; unsigned u; } v; v.u = ((unsigned)h) << 16;
    return v.f;
}

// ws byte offsets -------------------------------------------------------------
// fA_hi/fA_lo : [B][256 rt][64 lane][8] bf16   (A-frag of f^T == B-frag of f)
// gB_hi/gB_lo : [B][256 mt][64 lane][8] bf16   (B-frag of g  == A-frag of g^T)
// hB          : [B][128 mc][2 kt][64 lane][8]  (B-frag of h, perm order)
// WA_hi/WA_lo : [6 rt][8 cc][64 lane][8] bf16  (A-frag of [Wf;Wg;Wh])
// oT          : [B][4096 n][32 k] f32 (normalized o_pre^T)
// rcp_g       : [B][4096 n] f32  (1 / softmax row sums)
#define OFF_FA_HI (0)
#define OFF_FA_LO (1u<<20)
#define OFF_GB_HI (2u<<20)
#define OFF_GB_LO (3u<<20)
#define OFF_HB    (4u<<20)
#define OFF_WA_HI (5u<<20)
#define OFF_WA_LO ((5u<<20) + 65536)
#define OFF_OT    ((5u<<20) + 131072)
#define OFF_RCP   ((5u<<20) + 131072 + (2u<<20))

// ---------------- wt: W' = [Wf;Wg;Wh] -> A-fragments hi/lo -------------------
__global__ __launch_bounds__(256) void wt_kernel(const float* __restrict__ Wf,
                                                 const float* __restrict__ Wg,
                                                 const float* __restrict__ Wh,
                                                 unsigned short* __restrict__ WA_hi,
                                                 unsigned short* __restrict__ WA_lo)
{
    int t = blockIdx.x * 256 + threadIdx.x;      // 48 tiles * 64 lanes
    if (t >= 48 * 64) return;
    int tile = t >> 6, lane = t & 63;
    int rt = tile >> 3, cc = tile & 7;
    int q = lane >> 4, c15 = lane & 15;
    int row = rt * 16 + c15;
    const float* W = (row < 32) ? (Wf + (size_t)row * CDIM)
                   : (row < 64) ? (Wg + (size_t)(row - 32) * CDIM)
                                : (Wh + (size_t)(row - 64) * CDIM);
    int cb = cc * 32 + q * 8;
    bfrag vh, vl;
#pragma unroll
    for (int j = 0; j < 8; ++j) {
        float xv = W[cb + j];
        unsigned short h = f2bf(xv);
        vh[j] = (short)h;
        vl[j] = (short)f2bf(xv - bf2f(h));
    }
    *(bfrag*)(WA_hi + (size_t)t * 8) = vh;
    *(bfrag*)(WA_lo + (size_t)t * 8) = vl;
}

// ---------------- proj: MFMA GEMM [96 x 256] x [256 x n] -> fragments --------
__global__ __launch_bounds__(256) void proj_kernel(const float* __restrict__ x,
                                                   const unsigned short* __restrict__ WA_hi,
                                                   const unsigned short* __restrict__ WA_lo,
                                                   const float* __restrict__ bfv,
                                                   const float* __restrict__ bgv,
                                                   const float* __restrict__ bhv,
                                                   unsigned short* __restrict__ fA_hi,
                                                   unsigned short* __restrict__ fA_lo,
                                                   unsigned short* __restrict__ gB_hi,
                                                   unsigned short* __restrict__ gB_lo,
                                                   unsigned short* __restrict__ hB)
{
    __shared__ float xs[32][65];
    __shared__ float os[96][65];
    __shared__ float bias_s[96];

    const int b  = blockIdx.y;
    const int n0 = blockIdx.x * 64;
    const int tid = threadIdx.x;
    const int w = tid >> 6, lane = tid & 63, q = lane >> 4, c15 = lane & 15;

    if (tid < 96)
        bias_s[tid] = (tid < 32) ? bfv[tid] : (tid < 64 ? bgv[tid - 32] : bhv[tid - 64]);

    facc acc[6];
#pragma unroll
    for (int rt = 0; rt < 6; ++rt) acc[rt] = (facc){0.f, 0.f, 0.f, 0.f};

    const float* xb = x + (size_t)b * CDIM * NPIX + n0;
    const int cr = tid >> 3, nb = (tid & 7) * 8;

    for (int cc = 0; cc < 8; ++cc) {
        const float* src = xb + (size_t)(cc * 32 + cr) * NPIX + nb;
        float4 va = *(const float4*)src;
        float4 vb = *(const float4*)(src + 4);
        __syncthreads();
        *(float4*)&xs[cr][nb]     = va;
        *(float4*)&xs[cr][nb + 4] = vb;
        __syncthreads();

        bfrag xh, xl;
#pragma unroll
        for (int j = 0; j < 8; ++j) {
            float xv = xs[q * 8 + j][w * 16 + c15];
            unsigned short h = f2bf(xv);
            xh[j] = (short)h;
            xl[j] = (short)f2bf(xv - bf2f(h));
        }
#pragma unroll
        for (int rt = 0; rt < 6; ++rt) {
            size_t wo = ((size_t)(rt * 8 + cc) * 64 + lane) * 8;
            bfrag wh = *(const bfrag*)(WA_hi + wo);
            bfrag wl = *(const bfrag*)(WA_lo + wo);
            acc[rt] = MFMA(wh, xh, acc[rt]);
            acc[rt] = MFMA(wh, xl, acc[rt]);
            acc[rt] = MFMA(wl, xh, acc[rt]);
        }
    }

    // C-frag (col=lane&15, row=quad*4+i) -> os[row][n_local], add bias
#pragma unroll
    for (int rt = 0; rt < 6; ++rt)
#pragma unroll
        for (int i = 0; i < 4; ++i) {
            int row = rt * 16 + q * 4 + i;
            os[row][w * 16 + c15] = acc[rt][i] + bias_s[row];
        }
    __syncthreads();

    // fragment outputs: wave w handles n-tile w / h-unit w
    {
        bfrag vh, vl;
        // fA (rows 0..31): element j -> k = q*8+j, row (of A) = n
#pragma unroll
        for (int j = 0; j < 8; ++j) {
            float v = os[q * 8 + j][w * 16 + c15];
            unsigned short h = f2bf(v);
            vh[j] = (short)h; vl[j] = (short)f2bf(v - bf2f(h));
        }
        size_t o = ((size_t)(b * 256 + (n0 >> 4) + w) * 64 + lane) * 8;
        *(bfrag*)(fA_hi + o) = vh;
        *(bfrag*)(fA_lo + o) = vl;
        // gB (rows 32..63): element j -> k = q*8+j, col = n
#pragma unroll
        for (int j = 0; j < 8; ++j) {
            float v = os[32 + q * 8 + j][w * 16 + c15];
            unsigned short h = f2bf(v);
            vh[j] = (short)h; vl[j] = (short)f2bf(v - bf2f(h));
        }
        *(bfrag*)(gB_hi + o) = vh;
        *(bfrag*)(gB_lo + o) = vl;
        // hB (rows 64..95): B[m][k], contraction m in permuted physical order
        int mcl = w >> 1, kt = w & 1;
        bfrag hv;
#pragma unroll
        for (int j = 0; j < 8; ++j) {
            int p = q * 8 + j;
            int mp = (p & 1) * 16 + (p >> 1);          // perm: phys -> logical m
            float v = os[64 + kt * 16 + c15][mcl * 32 + mp];
            hv[j] = (short)f2bf(v);
        }
        size_t oh = ((size_t)((b * 128 + (n0 >> 5) + mcl) * 2 + kt) * 64 + lane) * 8;
        *(bfrag*)(hB + oh) = hv;
    }
}

// ---------------- attn pass 1: rowsums + o_pre (PV), persist rcp -------------
__global__ __launch_bounds__(256) void attn_kernel(const unsigned short* __restrict__ fA_hi,
                                                   const unsigned short* __restrict__ fA_lo,
                                                   const unsigned short* __restrict__ gB_hi,
                                                   const unsigned short* __restrict__ gB_lo,
                                                   const unsigned short* __restrict__ hB,
                                                   float* __restrict__ rcp_g,
                                                   float* __restrict__ oT)
{
    __shared__ unsigned short Pst[4][16 * 40];  // per-wave P tile, row stride 40 bf16
    __shared__ float red[4][64][8];             // cross-wave o_pre reduce
    __shared__ float sums_l[4][16];
    __shared__ float rcp_l[16];

    const int b  = blockIdx.y;
    const int r0 = blockIdx.x * 16;
    const int tid = threadIdx.x;
    const int w = tid >> 6, lane = tid & 63, q = lane >> 4, c15 = lane & 15;

    const size_t fo = ((size_t)(b * 256 + (r0 >> 4)) * 64 + lane) * 8;
    const bfrag fh = *(const bfrag*)(fA_hi + fo);
    const bfrag fl = *(const bfrag*)(fA_lo + fo);

    facc o0 = (facc){0.f,0.f,0.f,0.f}, o1 = (facc){0.f,0.f,0.f,0.f};
    float sum[4] = {0.f, 0.f, 0.f, 0.f};
    unsigned short* P = &Pst[w][0];

    const int ch0 = w * 32, ch1 = ch0 + 32;

    for (int mc = ch0; mc < ch1; ++mc) {
        size_t go = ((size_t)(b * 256 + 2 * mc) * 64 + lane) * 8;
        bfrag g0h = *(const bfrag*)(gB_hi + go);
        bfrag g1h = *(const bfrag*)(gB_hi + go + 512);
        bfrag g0l = *(const bfrag*)(gB_lo + go);
        bfrag g1l = *(const bfrag*)(gB_lo + go + 512);
        size_t ho = ((size_t)(b * 128 + mc) * 2 * 64 + lane) * 8;
        bfrag h0 = *(const bfrag*)(hB + ho);
        bfrag h1 = *(const bfrag*)(hB + ho + 512);

        facc s0 = (facc){0.f,0.f,0.f,0.f}, s1 = (facc){0.f,0.f,0.f,0.f};
        s0 = MFMA(fh, g0h, s0); s0 = MFMA(fh, g0l, s0); s0 = MFMA(fl, g0h, s0);
        s1 = MFMA(fh, g1h, s1); s1 = MFMA(fh, g1l, s1); s1 = MFMA(fl, g1h, s1);

        float e0[4], e1[4];
#pragma unroll
        for (int i = 0; i < 4; ++i) {
            e0[i] = __expf(s0[i] - SSHIFT);
            e1[i] = __expf(s1[i] - SSHIFT);
            sum[i] += e0[i] + e1[i];
        }
        // stage P in A-frag-compatible physical order: pair (m, m+16) adjacent
#pragma unroll
        for (int i = 0; i < 4; ++i) {
            unsigned pr = (unsigned)f2bf(e0[i]) | ((unsigned)f2bf(e1[i]) << 16);
            *(unsigned*)&P[(4 * q + i) * 40 + 2 * c15] = pr;
        }
        bfrag pA = *(const bfrag*)&P[c15 * 40 + q * 8];
        o0 = MFMA(pA, h0, o0);
        o1 = MFMA(pA, h1, o1);
    }

    // reduce rowsums over the 16 col-lanes of each quad
#pragma unroll
    for (int m = 1; m < 16; m <<= 1)
#pragma unroll
        for (int i = 0; i < 4; ++i) sum[i] += __shfl_xor(sum[i], m);
    if (c15 == 0) {
#pragma unroll
        for (int i = 0; i < 4; ++i) sums_l[w][4 * q + i] = sum[i];
    }
    *(facc*)&red[w][lane][0] = o0;
    *(facc*)&red[w][lane][4] = o1;
    __syncthreads();
    if (tid < 16) {
        float rv = 1.0f / (sums_l[0][tid] + sums_l[1][tid] + sums_l[2][tid] + sums_l[3][tid]);
        rcp_l[tid] = rv;
        rcp_g[(size_t)b * NPIX + r0 + tid] = rv;
    }
    __syncthreads();

    if (w == 0) {   // reduce o_pre across waves, normalize, store oT
        facc a = (facc){0.f,0.f,0.f,0.f}, bb = (facc){0.f,0.f,0.f,0.f};
#pragma unroll
        for (int ww = 0; ww < 4; ++ww) {
            a  += *(const facc*)&red[ww][lane][0];
            bb += *(const facc*)&red[ww][lane][4];
        }
#pragma unroll
        for (int i = 0; i < 4; ++i) {
            int r = 4 * q + i;
            float rc = rcp_l[r];
            oT[((size_t)(b * NPIX + r0 + r)) * KD + c15]      = a[i] * rc;
            oT[((size_t)(b * NPIX + r0 + r)) * KD + 16 + c15] = bb[i] * rc;
        }
    }
}

// ---------------- attn pass 2: m-major recompute, streaming am writes --------
// Block owns 16 m-rows; wave w sweeps n in [w*1024, (w+1)*1024).
// gB frags reinterpret as A-frags of g^T (rows=m); fA frags as B-frags of f
// (cols=n): D[row=m_local][col=n_local] = s^T tile.  Each 128B line of am is
// completed by the same wave in two consecutive iterations -> full-line
// writebacks, sequential store streams per row.
__global__ __launch_bounds__(256) void attn2_kernel(const unsigned short* __restrict__ fA_hi,
                                                    const unsigned short* __restrict__ fA_lo,
                                                    const unsigned short* __restrict__ gB_hi,
                                                    const unsigned short* __restrict__ gB_lo,
                                                    const float* __restrict__ rcp_g,
                                                    float* __restrict__ am)
{
    const int b   = blockIdx.y;
    const int mt  = blockIdx.x;                 // 16 m-rows
    const int tid = threadIdx.x;
    const int w = tid >> 6, lane = tid & 63, q = lane >> 4, c15 = lane & 15;

    const size_t ga = ((size_t)(b * 256 + mt) * 64 + lane) * 8;
    const bfrag a_hi = *(const bfrag*)(gB_hi + ga);
    const bfrag a_lo = *(const bfrag*)(gB_lo + ga);

    const int m0 = mt * 16 + q * 4;             // this quad's first m-row
    float* amrow = am + (size_t)b * NPIX * NPIX + (size_t)m0 * NPIX;
    const float* rcp_b = rcp_g + (size_t)b * NPIX;

#pragma unroll 2
    for (int t = 0; t < 64; ++t) {
        const int nt = w * 64 + t;
        const size_t fo = ((size_t)(b * 256 + nt) * 64 + lane) * 8;
        bfrag b_hi = *(const bfrag*)(fA_hi + fo);
        bfrag b_lo = *(const bfrag*)(fA_lo + fo);

        facc s = (facc){0.f,0.f,0.f,0.f};
        s = MFMA(a_hi, b_hi, s);
        s = MFMA(a_hi, b_lo, s);
        s = MFMA(a_lo, b_hi, s);

        const int n = nt * 16 + c15;
        const float rc = rcp_b[n];
#pragma unroll
        for (int i = 0; i < 4; ++i)
            amrow[(size_t)i * NPIX + n] = __expf(s[i] - SSHIFT) * rc;
    }
}

// ---------------- out: y = gamma*(Wv@o_pre + bv) + x -------------------------
__global__ __launch_bounds__(256) void out_kernel(const float* __restrict__ x,
                                                  const float* __restrict__ oT,
                                                  const float* __restrict__ Wv,
                                                  const float* __restrict__ bv,
                                                  const float* __restrict__ gamma,
                                                  float* __restrict__ y)
{
    __shared__ float wv_s[CDIM * KD];   // 32 KB
    const int b  = blockIdx.y;
    const int tid = threadIdx.x;
    const int n = blockIdx.x * 64 + (tid & 63);
    const int cg = tid >> 6;

    for (int i = tid * 4; i < CDIM * KD; i += 1024)
        *(float4*)&wv_s[i] = *(const float4*)&Wv[i];

    float op[KD];
    {
        const float4* src = (const float4*)&oT[((size_t)(b * NPIX + n)) * KD];
#pragma unroll
        for (int qq = 0; qq < 8; ++qq) {
            float4 v = src[qq];
            op[qq * 4 + 0] = v.x; op[qq * 4 + 1] = v.y;
            op[qq * 4 + 2] = v.z; op[qq * 4 + 3] = v.w;
        }
    }
    __syncthreads();
    const float gm = gamma[0];

    for (int c = cg * 64; c < cg * 64 + 64; ++c) {
        float a = 0.f;
#pragma unroll
        for (int k4 = 0; k4 < 8; ++k4) {
            float4 wv4 = *(const float4*)&wv_s[c * KD + k4 * 4];
            a = fmaf(wv4.x, op[k4 * 4 + 0], a);
            a = fmaf(wv4.y, op[k4 * 4 + 1], a);
            a = fmaf(wv4.z, op[k4 * 4 + 2], a);
            a = fmaf(wv4.w, op[k4 * 4 + 3], a);
        }
        size_t idx = ((size_t)(b * CDIM + c)) * NPIX + n;
        y[idx] = fmaf(gm, a + bv[c], x[idx]);
    }
}

extern "C" void kernel_launch(void* const* d_in, const int* in_sizes, int n_in,
                              void* d_out, int out_size, void* d_ws, size_t ws_size,
                              hipStream_t stream)
{
    const float* x     = (const float*)d_in[0];
    const float* Wf    = (const float*)d_in[1];
    const float* bfv   = (const float*)d_in[2];
    const float* Wg    = (const float*)d_in[3];
    const float* bgv   = (const float*)d_in[4];
    const float* Wh    = (const float*)d_in[5];
    const float* bhv   = (const float*)d_in[6];
    const float* Wv    = (const float*)d_in[7];
    const float* bv    = (const float*)d_in[8];
    const float* gamma = (const float*)d_in[9];

    char* ws = (char*)d_ws;
    unsigned short* fA_hi = (unsigned short*)(ws + OFF_FA_HI);
    unsigned short* fA_lo = (unsigned short*)(ws + OFF_FA_LO);
    unsigned short* gB_hi = (unsigned short*)(ws + OFF_GB_HI);
    unsigned short* gB_lo = (unsigned short*)(ws + OFF_GB_LO);
    unsigned short* hB    = (unsigned short*)(ws + OFF_HB);
    unsigned short* WA_hi = (unsigned short*)(ws + OFF_WA_HI);
    unsigned short* WA_lo = (unsigned short*)(ws + OFF_WA_LO);
    float*          oT    = (float*)(ws + OFF_OT);
    float*          rcp_g = (float*)(ws + OFF_RCP);

    float* y  = (float*)d_out;
    float* am = (float*)d_out + (size_t)NB * CDIM * NPIX;

    hipLaunchKernelGGL(wt_kernel, dim3(12), dim3(256), 0, stream, Wf, Wg, Wh, WA_hi, WA_lo);
    hipLaunchKernelGGL(proj_kernel, dim3(NPIX / 64, NB), dim3(256), 0, stream,
                       x, WA_hi, WA_lo, bfv, bgv, bhv, fA_hi, fA_lo, gB_hi, gB_lo, hB);
    hipLaunchKernelGGL(attn_kernel, dim3(NPIX / 16, NB), dim3(256), 0, stream,
                       fA_hi, fA_lo, gB_hi, gB_lo, hB, rcp_g, oT);
    hipLaunchKernelGGL(attn2_kernel, dim3(NPIX / 16, NB), dim3(256), 0, stream,
                       fA_hi, fA_lo, gB_hi, gB_lo, rcp_g, am);
    hipLaunchKernelGGL(out_kernel, dim3(NPIX / 64, NB), dim3(256), 0, stream,
                       x, oT, Wv, bv, gamma, y);
}